// Round 2
// baseline (356.629 us; speedup 1.0000x reference)
//
#include <hip/hip_runtime.h>

typedef float fvec4 __attribute__((ext_vector_type(4)));
typedef float f32x4 __attribute__((ext_vector_type(4)));
typedef short bf16x8 __attribute__((ext_vector_type(8)));

#define D   128   // D_IN == D_OUT
#define CAP 32    // per-direction adjacency slots (deg ~ Poisson(6), max ~25)

static __device__ __forceinline__ unsigned bcu(float f) {
    return __builtin_bit_cast(unsigned, f);
}
// pack two fp32 (round-half-up to bf16) into one u32 (lo elem in low half)
static __device__ __forceinline__ unsigned pack_bf2(float f0, float f1) {
    unsigned a0 = bcu(f0) + 0x8000u;
    unsigned a1 = bcu(f1) + 0x8000u;
    return __builtin_amdgcn_perm(a1, a0, 0x07060302u);
}
// full-precision RNE for the (tiny) weight prep
static __device__ __forceinline__ unsigned short f2bf_rne(float f) {
    unsigned u = bcu(f);
    u += 0x7FFFu + ((u >> 16) & 1u);
    return (unsigned short)(u >> 16);
}
static __device__ __forceinline__ float bflo(unsigned u) {
    return __builtin_bit_cast(float, u << 16);
}
static __device__ __forceinline__ float bfhi(unsigned u) {
    return __builtin_bit_cast(float, u & 0xFFFF0000u);
}

// ---------------------------------------------------------------------------
// P0: swizzled, transposed weight triple Wsw (bf16).
// Pass order: p=0 -> W_s (self pass first), p=1 -> W_f, p=2 -> W_b.
// Element t: p=t>>14, e=t&16383, row=e>>7 (output col j), c=e&127,
// u=(c>>3)^(row&15), k=u*8+(c&7), value = W_p[k][row].
// Swizzle keeps global->LDS staging a linear lane-order copy while making
// the GEMM's ds_read_b128 conflict-free.
// ---------------------------------------------------------------------------
__global__ __launch_bounds__(256) void prep_w(
    const float* __restrict__ Wf, const float* __restrict__ Wb,
    const float* __restrict__ Ws, unsigned short* __restrict__ Wsw)
{
    int t = blockIdx.x * 256 + threadIdx.x;
    if (t >= 3 * 128 * 128) return;
    int p   = t >> 14;
    int e   = t & 16383;
    int row = e >> 7;
    int c   = e & 127;
    int u   = (c >> 3) ^ (row & 15);
    int k   = u * 8 + (c & 7);
    const float* W = (p == 0) ? Ws : (p == 1) ? Wf : Wb;
    Wsw[t] = f2bf_rne(W[k * D + row]);
}

// ---------------------------------------------------------------------------
// K1: adjacency fill (blocks [0,Nfill)) + x -> bf16 convert (rest).
// ONE thread per edge handles BOTH directions: the two atomics issue
// back-to-back (independent RTTs in flight), index loads once per edge.
// Direction-split counters: [0,N) = fwd dest (recv, src=send),
//                           [N,2N) = bwd dest (send, src=recv).
// ---------------------------------------------------------------------------
__global__ __launch_bounds__(256) void conv_fill(
    const float* __restrict__ x, unsigned short* __restrict__ xb,
    const int* __restrict__ send, const int* __restrict__ recv,
    int* __restrict__ counts, int* __restrict__ adj,
    int N, int E, int Nfill)
{
    const int bid = blockIdx.x;
    if (bid < Nfill) {
        int e = bid * 256 + threadIdx.x;
        if (e < E) {
            int s = send[e];
            int r = recv[e];
            int p0 = atomicAdd(counts + r, 1);       // fwd: x[send] -> recv
            int p1 = atomicAdd(counts + N + s, 1);   // bwd: x[recv] -> send
            if (p0 < CAP) adj[(size_t)r * CAP + p0] = s;
            if (p1 < CAP) adj[((size_t)(N + s)) * CAP + p1] = r;
        }
        return;
    }
    // convert: 8 floats / thread
    size_t base = ((size_t)(bid - Nfill) * 256 + threadIdx.x) * 8;
    if (base >= (size_t)N * D) return;
    fvec4 a = *(const fvec4*)(x + base);
    fvec4 b = *(const fvec4*)(x + base + 4);
    uint4 p;
    p.x = pack_bf2(a[0], a[1]);
    p.y = pack_bf2(a[2], a[3]);
    p.z = pack_bf2(b[0], b[1]);
    p.w = pack_bf2(b[2], b[3]);
    *(uint4*)(xb + base) = p;
}

// ---------------------------------------------------------------------------
// K2 (fused): gather + 3-pass MFMA GEMM + dropout + relu -> out.
// 64 rows x 128 cols per block, 4 waves, wave tile 16 rows. One accumulator:
//   pass0: C  = xb @ W_s     (fragments direct from xb)
//   mask:  C *= dropout
//   pass1: C += S_f @ W_f    (S_f gathered IN-REGISTER, no Sm round-trip)
//   pass2: C += S_b @ W_b
// Gather: lane (quad,m16) accumulates xb[src][kc*32+quad*8 ..+8] in fp32 --
// exactly the MFMA B-fragment layout -- then packs once to bf16.
// counts/adj reads for a wave cover 16 CONSECUTIVE vertices (coalesced);
// src rows are random but xb (25.6 MB) is L3-resident. 2-deep src prefetch
// breaks the ap->xb dependency chain. W staging overlaps the gathers.
// ---------------------------------------------------------------------------
__global__ __launch_bounds__(256, 4) void gemm_fused(
    const unsigned short* __restrict__ xb,
    const unsigned short* __restrict__ Wsw,
    const float* __restrict__ drop_u,
    const int* __restrict__ counts, const int* __restrict__ adj,
    float* __restrict__ out, int N)
{
    __shared__ unsigned short ldsW[128 * 128];   // 32 KB, one pass of W

    const int wave = threadIdx.x >> 6;
    const int lane = threadIdx.x & 63;
    const int quad = lane >> 4;
    const int m16  = lane & 15;
    const int row  = blockIdx.x * 64 + wave * 16 + m16;
    const int rowc = (row < N) ? row : N - 1;     // clamp loads; stores guarded

    auto stage = [&](int p) {
        const char* src = (const char*)(Wsw + (size_t)p * 16384);
#pragma unroll
        for (int r = 0; r < 8; ++r) {
            const int unit = r * 256 + wave * 64;   // wave-uniform LDS base
            __builtin_amdgcn_global_load_lds(
                (const __attribute__((address_space(1))) unsigned*)
                    (src + (size_t)(unit + lane) * 16),
                (__attribute__((address_space(3))) unsigned*)
                    ((char*)ldsW + (size_t)unit * 16),
                16, 0, 0);
        }
    };

    stage(0);   // W_s

    // self-pass fragments (B-operand layout: elems kc*32 + quad*8 .. +8)
    const unsigned short* xp = xb + (size_t)rowc * D;
    bf16x8 xf[4];
#pragma unroll
    for (int kc = 0; kc < 4; ++kc)
        xf[kc] = *(const bf16x8*)(xp + kc * 32 + quad * 8);

    f32x4 C[8];
#pragma unroll
    for (int ct = 0; ct < 8; ++ct) C[ct] = (f32x4){0.f, 0.f, 0.f, 0.f};

    auto mfma_pass = [&]() {
#pragma unroll
        for (int kc = 0; kc < 4; ++kc) {
#pragma unroll
            for (int ct = 0; ct < 8; ++ct) {
                // swizzled LDS read: row = ct*16+m16, unit = (kc*4+quad)^m16
                const unsigned short* wp =
                    ldsW + (size_t)(ct * 16 + m16) * 128 +
                    (((kc * 4 + quad) ^ m16) * 8);
                bf16x8 wf = *(const bf16x8*)wp;
                C[ct] = __builtin_amdgcn_mfma_f32_16x16x32_bf16(
                    wf, xf[kc], C[ct], 0, 0, 0);
            }
        }
    };

    // in-register gather of one direction's neighbor sum -> xf
    auto gather_dir = [&](int base) {
        float s[4][8];
#pragma unroll
        for (int kc = 0; kc < 4; ++kc)
#pragma unroll
            for (int i = 0; i < 8; ++i) s[kc][i] = 0.0f;

        const int cv = base + rowc;
        int deg = counts[cv];
        if (deg > CAP) deg = CAP;
        const int* ap = adj + (size_t)cv * CAP;

        auto accum = [&](int src) {
            const unsigned short* sp = xb + (size_t)src * D + quad * 8;
            uint4 v0 = *(const uint4*)(sp);
            uint4 v1 = *(const uint4*)(sp + 32);
            uint4 v2 = *(const uint4*)(sp + 64);
            uint4 v3 = *(const uint4*)(sp + 96);
            s[0][0] += bflo(v0.x); s[0][1] += bfhi(v0.x);
            s[0][2] += bflo(v0.y); s[0][3] += bfhi(v0.y);
            s[0][4] += bflo(v0.z); s[0][5] += bfhi(v0.z);
            s[0][6] += bflo(v0.w); s[0][7] += bfhi(v0.w);
            s[1][0] += bflo(v1.x); s[1][1] += bfhi(v1.x);
            s[1][2] += bflo(v1.y); s[1][3] += bfhi(v1.y);
            s[1][4] += bflo(v1.z); s[1][5] += bfhi(v1.z);
            s[1][6] += bflo(v1.w); s[1][7] += bfhi(v1.w);
            s[2][0] += bflo(v2.x); s[2][1] += bfhi(v2.x);
            s[2][2] += bflo(v2.y); s[2][3] += bfhi(v2.y);
            s[2][4] += bflo(v2.z); s[2][5] += bfhi(v2.z);
            s[2][6] += bflo(v2.w); s[2][7] += bfhi(v2.w);
            s[3][0] += bflo(v3.x); s[3][1] += bfhi(v3.x);
            s[3][2] += bflo(v3.y); s[3][3] += bfhi(v3.y);
            s[3][4] += bflo(v3.z); s[3][5] += bfhi(v3.z);
            s[3][6] += bflo(v3.w); s[3][7] += bfhi(v3.w);
        };

        // 2-deep prefetch of src indices breaks the ap->xb dependency chain
        int s0 = (0 < deg) ? ap[0] : 0;
        int s1 = (1 < deg) ? ap[1] : 0;
        int j = 0;
        while (__any(j < deg)) {
            int n0 = (j + 2 < deg) ? ap[j + 2] : 0;
            int n1 = (j + 3 < deg) ? ap[j + 3] : 0;
            if (j < deg)     accum(s0);
            if (j + 1 < deg) accum(s1);
            s0 = n0; s1 = n1;
            j += 2;
        }

#pragma unroll
        for (int kc = 0; kc < 4; ++kc) {
            uint4 p;
            p.x = pack_bf2(s[kc][0], s[kc][1]);
            p.y = pack_bf2(s[kc][2], s[kc][3]);
            p.z = pack_bf2(s[kc][4], s[kc][5]);
            p.w = pack_bf2(s[kc][6], s[kc][7]);
            xf[kc] = __builtin_bit_cast(bf16x8, p);
        }
    };

    __syncthreads();          // W_s staged (self fragments in flight)
    mfma_pass();              // C = x @ W_s
    __syncthreads();          // done reading ldsW
    stage(1);                 // W_f (overlaps mask + gather)

    // dropout mask on the self term only
    {
        fvec4 u[8];
#pragma unroll
        for (int ct = 0; ct < 8; ++ct)
            u[ct] = *(const fvec4*)(drop_u + (size_t)rowc * D + ct * 16 + quad * 4);
#pragma unroll
        for (int ct = 0; ct < 8; ++ct) {
#pragma unroll
            for (int c = 0; c < 4; ++c)
                C[ct][c] *= (u[ct][c] < 0.8f) ? 1.25f : 0.0f;
        }
    }

    gather_dir(0);            // S_f -> xf (hides under W_f staging)

    __syncthreads();          // W_f staged
    mfma_pass();              // C += S_f @ W_f
    __syncthreads();
    stage(2);                 // W_b

    gather_dir(N);            // S_b -> xf (hides under W_b staging)

    __syncthreads();          // W_b staged
    mfma_pass();              // C += S_b @ W_b

    if (row < N) {
#pragma unroll
        for (int ct = 0; ct < 8; ++ct) {
            fvec4 r;
#pragma unroll
            for (int c = 0; c < 4; ++c)
                r[c] = fmaxf(C[ct][c], 0.0f);
            *(fvec4*)(out + (size_t)row * D + ct * 16 + quad * 4) = r;
        }
    }
}

extern "C" void kernel_launch(void* const* d_in, const int* in_sizes, int n_in,
                              void* d_out, int out_size, void* d_ws, size_t ws_size,
                              hipStream_t stream)
{
    const float* x      = (const float*)d_in[0];
    const float* W_f    = (const float*)d_in[1];
    const float* W_b    = (const float*)d_in[2];
    const float* W_s    = (const float*)d_in[3];
    const float* drop_u = (const float*)d_in[4];
    const int*   send   = (const int*)d_in[5];
    const int*   recv   = (const int*)d_in[6];

    const int N = in_sizes[0] / D;   // 100000
    const int E = in_sizes[5];       // 600000

    float* out = (float*)d_out;

    // workspace layout (16B-aligned chunks):
    //   Wsw    : 3*128*128 bf16 (96 KB, pre-swizzled)
    //   xb     : N*128 bf16   (25.6 MB)  x in bf16
    //   counts : 2N ints      (0.8 MB)   fwd at [0,N), bwd at [N,2N)
    //   adj    : 2N*CAP ints  (25.6 MB)
    unsigned short* Wsw = (unsigned short*)d_ws;
    unsigned short* xb  = Wsw + (size_t)3 * 128 * 128;
    int* counts = (int*)(xb + (size_t)N * D);
    int* adj    = counts + (size_t)2 * N;

    const int Nfill = (E + 255) / 256;                // 2344 fill blocks
    const int Nconv = (N * D + 2047) / 2048;          // 6250 convert blocks
    const int Nb    = (N + 63) / 64;                  // 1563 GEMM blocks

    // P0: swizzled W prep (tiny)
    prep_w<<<(3 * 128 * 128 + 255) / 256, 256, 0, stream>>>(W_f, W_b, W_s, Wsw);

    // counts must start at zero (ws is poisoned each call)
    hipMemsetAsync(counts, 0, (size_t)2 * N * sizeof(int), stream);

    // K1: adjacency fill (first) + x->bf16 convert
    conv_fill<<<Nfill + Nconv, 256, 0, stream>>>(x, xb, send, recv,
                                                 counts, adj, N, E, Nfill);

    // K2: fused gather + 3-pass GEMM + dropout + relu -> out
    gemm_fused<<<Nb, 256, 0, stream>>>(xb, Wsw, drop_u, counts, adj, out, N);
}

// Round 3
// 307.426 us; speedup vs baseline: 1.1600x; 1.1600x over previous
//
#include <hip/hip_runtime.h>

typedef float fvec4 __attribute__((ext_vector_type(4)));
typedef float f32x4 __attribute__((ext_vector_type(4)));
typedef short bf16x8 __attribute__((ext_vector_type(8)));

#define D   128   // D_IN == D_OUT
#define CAP 32    // per-direction adjacency slots (deg ~ Poisson(6), max ~25)

static __device__ __forceinline__ unsigned bcu(float f) {
    return __builtin_bit_cast(unsigned, f);
}
// pack two fp32 (round-half-up to bf16) into one u32 (lo elem in low half)
static __device__ __forceinline__ unsigned pack_bf2(float f0, float f1) {
    unsigned a0 = bcu(f0) + 0x8000u;
    unsigned a1 = bcu(f1) + 0x8000u;
    return __builtin_amdgcn_perm(a1, a0, 0x07060302u);
}
// full-precision RNE for the (tiny) weight prep
static __device__ __forceinline__ unsigned short f2bf_rne(float f) {
    unsigned u = bcu(f);
    u += 0x7FFFu + ((u >> 16) & 1u);
    return (unsigned short)(u >> 16);
}
static __device__ __forceinline__ float bflo(unsigned u) {
    return __builtin_bit_cast(float, u << 16);
}
static __device__ __forceinline__ float bfhi(unsigned u) {
    return __builtin_bit_cast(float, u & 0xFFFF0000u);
}

// ---------------------------------------------------------------------------
// P0: swizzled, transposed weight triple Wsw (bf16).
// p=0 -> W_s (used by K1), p=1 -> W_f, p=2 -> W_b (used by K2).
// Element t: p=t>>14, e=t&16383, row=e>>7 (output col j), c=e&127,
// u=(c>>3)^(row&15), k=u*8+(c&7), value = W_p[k][row].
// Swizzle keeps global->LDS staging a linear lane-order copy while making
// the GEMM's ds_read_b128 conflict-free.
// ---------------------------------------------------------------------------
__global__ __launch_bounds__(256) void prep_w(
    const float* __restrict__ Wf, const float* __restrict__ Wb,
    const float* __restrict__ Ws, unsigned short* __restrict__ Wsw)
{
    int t = blockIdx.x * 256 + threadIdx.x;
    if (t >= 3 * 128 * 128) return;
    int p   = t >> 14;
    int e   = t & 16383;
    int row = e >> 7;
    int c   = e & 127;
    int u   = (c >> 3) ^ (row & 15);
    int k   = u * 8 + (c & 7);
    const float* W = (p == 0) ? Ws : (p == 1) ? Wf : Wb;
    Wsw[t] = f2bf_rne(W[k * D + row]);
}

// ---------------------------------------------------------------------------
// K1 (role-split): adjacency fill (blocks [0,Nfill), round-1 form: 2
// threads/edge, 1 atomic each -- measured 105 us standalone) + GEMM-S blocks
// that stream x -> xb (bf16) and compute the adjacency-INDEPENDENT self term
//   out[row] = dropout_mask * (x @ W_s)     (fp32, stored into d_out)
// The streaming/MFMA work rides the idle issue slots & BW of the
// atomic-latency-bound fill blocks (fill was 1.1% VALUBusy, 15% HBM).
// ---------------------------------------------------------------------------
__global__ __launch_bounds__(256, 4) void fill_gemmS(
    const float* __restrict__ x,
    const unsigned short* __restrict__ Wsw,
    const float* __restrict__ drop_u,
    unsigned short* __restrict__ xb,
    float* __restrict__ out,
    const int* __restrict__ send, const int* __restrict__ recv,
    int* __restrict__ counts, int* __restrict__ adj,
    int N, int E, int Nfill)
{
    __shared__ unsigned short ldsW[128 * 128];   // 32 KB (GEMM blocks only)

    const int bid = blockIdx.x;
    if (bid < Nfill) {
        // ---- adjacency fill ----
        int t = bid * 256 + threadIdx.x;
        int e = t >> 1;
        if (e < E) {
            int v, src;
            if (t & 1) { v = recv[e];     src = send[e]; }   // fwd: x[send]->recv
            else       { v = N + send[e]; src = recv[e]; }   // bwd: x[recv]->send
            int pos = atomicAdd(counts + v, 1);
            if (pos < CAP) adj[(size_t)v * CAP + pos] = src;
        }
        return;
    }

    // ---- GEMM-S ----
    const int gb   = bid - Nfill;
    const int wave = threadIdx.x >> 6;
    const int lane = threadIdx.x & 63;
    const int quad = lane >> 4;
    const int m16  = lane & 15;
    const int row  = gb * 64 + wave * 16 + m16;
    const int rowc = (row < N) ? row : N - 1;    // clamp loads; stores guarded

    // stage W_s (p=0) into LDS: 8 rounds x 256 lanes x 16 B linear copy
    {
        const char* src = (const char*)Wsw;
#pragma unroll
        for (int r = 0; r < 8; ++r) {
            const int unit = r * 256 + wave * 64;   // wave-uniform LDS base
            __builtin_amdgcn_global_load_lds(
                (const __attribute__((address_space(1))) unsigned*)
                    (src + (size_t)(unit + lane) * 16),
                (__attribute__((address_space(3))) unsigned*)
                    ((char*)ldsW + (size_t)unit * 16),
                16, 0, 0);
        }
    }

    // x row loads (B-fragment layout: elems kc*32 + quad*8 .. +8)
    const float* xp = x + (size_t)rowc * D;
    fvec4 xlo[4], xhi[4];
#pragma unroll
    for (int kc = 0; kc < 4; ++kc) {
        xlo[kc] = *(const fvec4*)(xp + kc * 32 + quad * 8);
        xhi[kc] = *(const fvec4*)(xp + kc * 32 + quad * 8 + 4);
    }
    fvec4 u[8];
#pragma unroll
    for (int ct = 0; ct < 8; ++ct)
        u[ct] = *(const fvec4*)(drop_u + (size_t)rowc * D + ct * 16 + quad * 4);

    // pack to bf16 fragments + emit xb (gather pool for K2)
    bf16x8 xf[4];
#pragma unroll
    for (int kc = 0; kc < 4; ++kc) {
        uint4 xi;
        xi.x = pack_bf2(xlo[kc][0], xlo[kc][1]);
        xi.y = pack_bf2(xlo[kc][2], xlo[kc][3]);
        xi.z = pack_bf2(xhi[kc][0], xhi[kc][1]);
        xi.w = pack_bf2(xhi[kc][2], xhi[kc][3]);
        xf[kc] = __builtin_bit_cast(bf16x8, xi);
        // clamped duplicate rows write identical bytes -> benign
        *(uint4*)(xb + (size_t)rowc * D + kc * 32 + quad * 8) = xi;
    }

    f32x4 C[8];
#pragma unroll
    for (int ct = 0; ct < 8; ++ct) C[ct] = (f32x4){0.f, 0.f, 0.f, 0.f};

    __syncthreads();          // W_s staged

#pragma unroll
    for (int kc = 0; kc < 4; ++kc) {
#pragma unroll
        for (int ct = 0; ct < 8; ++ct) {
            // swizzled LDS read: row = ct*16+m16, unit = (kc*4+quad)^m16
            const unsigned short* wp =
                ldsW + (size_t)(ct * 16 + m16) * 128 +
                (((kc * 4 + quad) ^ m16) * 8);
            bf16x8 wf = *(const bf16x8*)wp;
            C[ct] = __builtin_amdgcn_mfma_f32_16x16x32_bf16(
                wf, xf[kc], C[ct], 0, 0, 0);
        }
    }

    if (row < N) {
#pragma unroll
        for (int ct = 0; ct < 8; ++ct) {
            fvec4 r;
#pragma unroll
            for (int c = 0; c < 4; ++c)
                r[c] = C[ct][c] * ((u[ct][c] < 0.8f) ? 1.25f : 0.0f);
            *(fvec4*)(out + (size_t)row * D + ct * 16 + quad * 4) = r;
        }
    }
}

// ---------------------------------------------------------------------------
// K2: in-register gather + 2-pass MFMA GEMM + self-term add + relu.
//   C  = S_f @ W_f   (S_f gathered in-register, fp32 accum, one bf16 round)
//   C += S_b @ W_b
//   out = relu(C + out)        (out holds the K1 self term, fp32)
// Gather: lane (quad,m16) accumulates xb[src][quad's 32 elems] -- exactly
// the MFMA B-fragment layout. W staging overlaps the gathers. Self-term
// loads issued before the last MFMA pass (latency hidden under it).
// Nontemporal on the out read/write: write-once/read-once data must not
// hold L2 lines against the gather stream (round-2 showed 3x write
// amplification from exactly that thrash).
// ---------------------------------------------------------------------------
__global__ __launch_bounds__(256, 4) void gather_gemm(
    const unsigned short* __restrict__ xb,
    const unsigned short* __restrict__ Wsw,
    const int* __restrict__ counts, const int* __restrict__ adj,
    float* __restrict__ out, int N)
{
    __shared__ unsigned short ldsW[128 * 128];   // 32 KB, one pass of W

    const int wave = threadIdx.x >> 6;
    const int lane = threadIdx.x & 63;
    const int quad = lane >> 4;
    const int m16  = lane & 15;
    const int row  = blockIdx.x * 64 + wave * 16 + m16;
    const int rowc = (row < N) ? row : N - 1;

    auto stage = [&](int p) {
        const char* src = (const char*)(Wsw + (size_t)p * 16384);
#pragma unroll
        for (int r = 0; r < 8; ++r) {
            const int unit = r * 256 + wave * 64;   // wave-uniform LDS base
            __builtin_amdgcn_global_load_lds(
                (const __attribute__((address_space(1))) unsigned*)
                    (src + (size_t)(unit + lane) * 16),
                (__attribute__((address_space(3))) unsigned*)
                    ((char*)ldsW + (size_t)unit * 16),
                16, 0, 0);
        }
    };

    f32x4 C[8];
#pragma unroll
    for (int ct = 0; ct < 8; ++ct) C[ct] = (f32x4){0.f, 0.f, 0.f, 0.f};

    bf16x8 xf[4];

    // in-register gather of one direction's neighbor sum -> xf
    auto gather_dir = [&](int base) {
        float s[4][8];
#pragma unroll
        for (int kc = 0; kc < 4; ++kc)
#pragma unroll
            for (int i = 0; i < 8; ++i) s[kc][i] = 0.0f;

        const int cv = base + rowc;
        int deg = counts[cv];
        if (deg > CAP) deg = CAP;
        const int* ap = adj + (size_t)cv * CAP;

        auto accum = [&](int src) {
            const unsigned short* sp = xb + (size_t)src * D + quad * 8;
            uint4 v0 = *(const uint4*)(sp);
            uint4 v1 = *(const uint4*)(sp + 32);
            uint4 v2 = *(const uint4*)(sp + 64);
            uint4 v3 = *(const uint4*)(sp + 96);
            s[0][0] += bflo(v0.x); s[0][1] += bfhi(v0.x);
            s[0][2] += bflo(v0.y); s[0][3] += bfhi(v0.y);
            s[0][4] += bflo(v0.z); s[0][5] += bfhi(v0.z);
            s[0][6] += bflo(v0.w); s[0][7] += bfhi(v0.w);
            s[1][0] += bflo(v1.x); s[1][1] += bfhi(v1.x);
            s[1][2] += bflo(v1.y); s[1][3] += bfhi(v1.y);
            s[1][4] += bflo(v1.z); s[1][5] += bfhi(v1.z);
            s[1][6] += bflo(v1.w); s[1][7] += bfhi(v1.w);
            s[2][0] += bflo(v2.x); s[2][1] += bfhi(v2.x);
            s[2][2] += bflo(v2.y); s[2][3] += bfhi(v2.y);
            s[2][4] += bflo(v2.z); s[2][5] += bfhi(v2.z);
            s[2][6] += bflo(v2.w); s[2][7] += bfhi(v2.w);
            s[3][0] += bflo(v3.x); s[3][1] += bfhi(v3.x);
            s[3][2] += bflo(v3.y); s[3][3] += bfhi(v3.y);
            s[3][4] += bflo(v3.z); s[3][5] += bfhi(v3.z);
            s[3][6] += bflo(v3.w); s[3][7] += bfhi(v3.w);
        };

        // 2-deep prefetch of src indices breaks the ap->xb dependency chain
        int s0 = (0 < deg) ? ap[0] : 0;
        int s1 = (1 < deg) ? ap[1] : 0;
        int j = 0;
        while (__any(j < deg)) {
            int n0 = (j + 2 < deg) ? ap[j + 2] : 0;
            int n1 = (j + 3 < deg) ? ap[j + 3] : 0;
            if (j < deg)     accum(s0);
            if (j + 1 < deg) accum(s1);
            s0 = n0; s1 = n1;
            j += 2;
        }

#pragma unroll
        for (int kc = 0; kc < 4; ++kc) {
            uint4 p;
            p.x = pack_bf2(s[kc][0], s[kc][1]);
            p.y = pack_bf2(s[kc][2], s[kc][3]);
            p.z = pack_bf2(s[kc][4], s[kc][5]);
            p.w = pack_bf2(s[kc][6], s[kc][7]);
            xf[kc] = __builtin_bit_cast(bf16x8, p);
        }
    };

    auto mfma_pass = [&]() {
#pragma unroll
        for (int kc = 0; kc < 4; ++kc) {
#pragma unroll
            for (int ct = 0; ct < 8; ++ct) {
                const unsigned short* wp =
                    ldsW + (size_t)(ct * 16 + m16) * 128 +
                    (((kc * 4 + quad) ^ m16) * 8);
                bf16x8 wf = *(const bf16x8*)wp;
                C[ct] = __builtin_amdgcn_mfma_f32_16x16x32_bf16(
                    wf, xf[kc], C[ct], 0, 0, 0);
            }
        }
    };

    stage(1);                 // W_f (async; overlaps the fwd gather)
    gather_dir(0);            // S_f -> xf

    __syncthreads();          // W_f staged
    mfma_pass();              // C = S_f @ W_f
    __syncthreads();          // done reading ldsW
    stage(2);                 // W_b (overlaps the bwd gather)

    gather_dir(N);            // S_b -> xf

    // self-term loads: issue now, consumed after the last MFMA pass
    fvec4 t[8];
    if (row < N) {
#pragma unroll
        for (int ct = 0; ct < 8; ++ct)
            t[ct] = __builtin_nontemporal_load(
                (const fvec4*)(out + (size_t)row * D + ct * 16 + quad * 4));
    }

    __syncthreads();          // W_b staged
    mfma_pass();              // C += S_b @ W_b

    if (row < N) {
#pragma unroll
        for (int ct = 0; ct < 8; ++ct) {
            fvec4 r;
#pragma unroll
            for (int c = 0; c < 4; ++c)
                r[c] = fmaxf(C[ct][c] + t[ct][c], 0.0f);
            __builtin_nontemporal_store(
                r, (fvec4*)(out + (size_t)row * D + ct * 16 + quad * 4));
        }
    }
}

extern "C" void kernel_launch(void* const* d_in, const int* in_sizes, int n_in,
                              void* d_out, int out_size, void* d_ws, size_t ws_size,
                              hipStream_t stream)
{
    const float* x      = (const float*)d_in[0];
    const float* W_f    = (const float*)d_in[1];
    const float* W_b    = (const float*)d_in[2];
    const float* W_s    = (const float*)d_in[3];
    const float* drop_u = (const float*)d_in[4];
    const int*   send   = (const int*)d_in[5];
    const int*   recv   = (const int*)d_in[6];

    const int N = in_sizes[0] / D;   // 100000
    const int E = in_sizes[5];       // 600000

    float* out = (float*)d_out;

    // workspace layout (16B-aligned chunks):
    //   Wsw    : 3*128*128 bf16 (96 KB, pre-swizzled)
    //   xb     : N*128 bf16   (25.6 MB)  x in bf16 (gather pool)
    //   counts : 2N ints      (0.8 MB)   fwd at [0,N), bwd at [N,2N)
    //   adj    : 2N*CAP ints  (25.6 MB)
    // Self term lives in d_out (written by K1, consumed+overwritten by K2).
    unsigned short* Wsw = (unsigned short*)d_ws;
    unsigned short* xb  = Wsw + (size_t)3 * 128 * 128;
    int* counts = (int*)(xb + (size_t)N * D);
    int* adj    = counts + (size_t)2 * N;

    const int Nfill = (2 * E + 255) / 256;            // 4688 fill blocks
    const int Nb    = (N + 63) / 64;                  // 1563 GEMM blocks

    // P0: swizzled W prep (tiny)
    prep_w<<<(3 * 128 * 128 + 255) / 256, 256, 0, stream>>>(W_f, W_b, W_s, Wsw);

    // counts must start at zero (ws is poisoned each call)
    hipMemsetAsync(counts, 0, (size_t)2 * N * sizeof(int), stream);

    // K1: adjacency fill (first) overlapped with self-term GEMM + xb convert
    fill_gemmS<<<Nfill + Nb, 256, 0, stream>>>(
        x, Wsw, drop_u, xb, out, send, recv, counts, adj, N, E, Nfill);

    // K2: gather + 2-pass GEMM + self add + relu -> out
    gather_gemm<<<Nb, 256, 0, stream>>>(xb, Wsw, counts, adj, out, N);
}